// Round 2
// baseline (267.439 us; speedup 1.0000x reference)
//
#include <hip/hip_runtime.h>
#include <hip/hip_bf16.h>

// Problem dims (fixed by reference): B=2, M=L=2048, H=1024, K_HEADS=16, D=64
// NOTE: all inputs and the output are FLOAT32 (reference dtype). We convert to
// bf16 for MFMA compute; f32 accumulation throughout.
#define BB 2
#define MM 2048
#define HH 1024
#define KH 16
#define DD 64

typedef short s16x8 __attribute__((ext_vector_type(8)));
typedef float f32x4 __attribute__((ext_vector_type(4)));

#define GLOBAL_AS __attribute__((address_space(1)))
#define LDS_AS    __attribute__((address_space(3)))

__device__ inline void async_copy16(const void* g, void* l) {
    __builtin_amdgcn_global_load_lds((const GLOBAL_AS void*)g, (LDS_AS void*)l, 16, 0, 0);
}

// ---------------------------------------------------------------------------
// fp32 -> bf16 conversion (vectorized: float4 in, 4x bf16 out)
// ---------------------------------------------------------------------------
struct bf16x4_t { __hip_bfloat16 x, y, z, w; };

__global__ __launch_bounds__(256) void cvt_f32_bf16(
    const float* __restrict__ src, __hip_bfloat16* __restrict__ dst, int n)
{
    const int i = (blockIdx.x * 256 + threadIdx.x) * 4;
    if (i + 3 < n) {
        const float4 v = *(const float4*)(src + i);
        bf16x4_t o;
        o.x = __float2bfloat16(v.x);
        o.y = __float2bfloat16(v.y);
        o.z = __float2bfloat16(v.z);
        o.w = __float2bfloat16(v.w);
        *(bf16x4_t*)(dst + i) = o;
    }
}

// ---------------------------------------------------------------------------
// NT GEMM: C[m,n] = sum_k A[m,k] * Bm[n,k]   (A: [Mrows,Kdim], Bm: [Ncols,Kdim])
// m97-style: 128x128 tile, BK=32, global_load_lds width 16, 16x16x32 bf16 MFMA
// OutT selects the C store type (float for final output, bf16 for intermediates)
// ---------------------------------------------------------------------------
__device__ inline void store_c(__hip_bfloat16* C, size_t idx, float v) {
    C[idx] = __float2bfloat16(v);
}
__device__ inline void store_c(float* C, size_t idx, float v) { C[idx] = v; }

template <typename OutT>
__global__ __launch_bounds__(256) void gemm_nt(
    const __hip_bfloat16* __restrict__ A,
    const __hip_bfloat16* __restrict__ Bm,
    OutT* __restrict__ C,
    int Mrows, int Ncols, int Kdim)
{
    __shared__ __align__(16) __hip_bfloat16 As[128 * 32];  // 8 KB
    __shared__ __align__(16) __hip_bfloat16 Bs[128 * 32];  // 8 KB

    const int t    = threadIdx.x;
    const int lane = t & 63;
    const int wave = t >> 6;
    const int m0   = blockIdx.x * 128;
    const int n0   = blockIdx.y * 128;

    // staging: chunk c = wave*2+i covers rows [c*16, c*16+16) of the tile.
    // lane -> row c*16 + (lane>>2), col elem (lane&3)*8; LDS dest = base + lane*16B.
    const int lr = lane >> 2;
    const int lc = (lane & 3) * 8;

    // fragment addressing
    const int wm = (wave >> 1) * 64;
    const int wn = (wave & 1) * 64;
    const int fr = lane & 15;
    const int fq = (lane >> 4) * 8;

    f32x4 acc[4][4] = {};

    for (int k0 = 0; k0 < Kdim; k0 += 32) {
        __syncthreads();  // WAR: previous tile reads done before overwrite
#pragma unroll
        for (int i = 0; i < 2; ++i) {
            const int c = wave * 2 + i;
            const __hip_bfloat16* ag = A  + (size_t)(m0 + c * 16 + lr) * Kdim + (k0 + lc);
            async_copy16(ag, As + c * 512);
            const __hip_bfloat16* bg = Bm + (size_t)(n0 + c * 16 + lr) * Kdim + (k0 + lc);
            async_copy16(bg, Bs + c * 512);
        }
        __syncthreads();  // RAW: barrier drains vmcnt for global_load_lds

        s16x8 af[4], bf[4];
#pragma unroll
        for (int mi = 0; mi < 4; ++mi)
            af[mi] = *(const s16x8*)(As + (wm + mi * 16 + fr) * 32 + fq);
#pragma unroll
        for (int ni = 0; ni < 4; ++ni)
            bf[ni] = *(const s16x8*)(Bs + (wn + ni * 16 + fr) * 32 + fq);
#pragma unroll
        for (int mi = 0; mi < 4; ++mi)
#pragma unroll
            for (int ni = 0; ni < 4; ++ni)
                acc[mi][ni] = __builtin_amdgcn_mfma_f32_16x16x32_bf16(
                    af[mi], bf[ni], acc[mi][ni], 0, 0, 0);
    }

    // epilogue: C/D layout col=lane&15 (n), row=(lane>>4)*4+r (m)  [m89-verified]
    const int er = (lane >> 4) * 4;
    const int ec = lane & 15;
#pragma unroll
    for (int mi = 0; mi < 4; ++mi)
#pragma unroll
        for (int ni = 0; ni < 4; ++ni)
#pragma unroll
            for (int r = 0; r < 4; ++r) {
                const int m = m0 + wm + mi * 16 + er + r;
                const int n = n0 + wn + ni * 16 + ec;
                store_c(C, (size_t)m * Ncols + n, acc[mi][ni][r]);
            }
}

// ---------------------------------------------------------------------------
// S[b,h,d1,d2] = sum_l K[b,l,h*64+d1] * V[b,l,h*64+d2]   (f32, atomic partials)
// grid: (8 L-chunks of 256, KH, BB); block 256
// ---------------------------------------------------------------------------
__global__ __launch_bounds__(256) void kv_outer(
    const __hip_bfloat16* __restrict__ Km,
    const __hip_bfloat16* __restrict__ Vm,
    float* __restrict__ S)
{
    const int chunk = blockIdx.x, head = blockIdx.y, b = blockIdx.z;
    const int t = threadIdx.x;
    const int d1b = (t >> 4) * 4;   // 4 d1 values
    const int d2b = (t & 15) * 4;   // 4 d2 values

    __shared__ float Kl[16][64];
    __shared__ float Vl[16][64];

    float acc[4][4] = {};
    const int l0 = chunk * 256;

    for (int c = 0; c < 16; ++c) {
        const int lbase = l0 + c * 16;
        __syncthreads();
        for (int idx = t; idx < 1024; idx += 256) {
            const int r = idx >> 6, col = idx & 63;
            const size_t g = (size_t)(b * MM + lbase + r) * HH + head * 64 + col;
            Kl[r][col] = __bfloat162float(Km[g]);
            Vl[r][col] = __bfloat162float(Vm[g]);
        }
        __syncthreads();
#pragma unroll
        for (int li = 0; li < 16; ++li) {
            float kv[4], vv[4];
#pragma unroll
            for (int i = 0; i < 4; ++i) kv[i] = Kl[li][d1b + i];
#pragma unroll
            for (int j = 0; j < 4; ++j) vv[j] = Vl[li][d2b + j];
#pragma unroll
            for (int i = 0; i < 4; ++i)
#pragma unroll
                for (int j = 0; j < 4; ++j)
                    acc[i][j] += kv[i] * vv[j];
        }
    }

    float* Sg = S + ((size_t)b * KH + head) * 64 * 64;
#pragma unroll
    for (int i = 0; i < 4; ++i)
#pragma unroll
        for (int j = 0; j < 4; ++j)
            atomicAdd(&Sg[(d1b + i) * 64 + (d2b + j)], acc[i][j]);
}

// ---------------------------------------------------------------------------
// Out[b,m,h*64+d] = sum_dp Q[b,m,h*64+dp] * S[b,h,dp,d]
// grid: (32 m-tiles of 64, KH, BB); block 256
// ---------------------------------------------------------------------------
__global__ __launch_bounds__(256) void q_times_s(
    const __hip_bfloat16* __restrict__ Q,
    const float* __restrict__ S,
    __hip_bfloat16* __restrict__ Out)
{
    const int mt = blockIdx.x, head = blockIdx.y, b = blockIdx.z;
    const int t = threadIdx.x;
    const int mb = (t >> 4) * 4;    // 4 m values (within 64-row tile)
    const int db = (t & 15) * 4;    // 4 d values

    __shared__ float Sl[64 * 64];   // Sl[dp*64 + d]
    __shared__ float Ql[64 * 64];   // Ql[m*64 + dp]

    const float* Sg = S + ((size_t)b * KH + head) * 4096;
    for (int idx = t; idx < 4096; idx += 256) Sl[idx] = Sg[idx];
    for (int idx = t; idx < 4096; idx += 256) {
        const int r = idx >> 6, c = idx & 63;
        Ql[idx] = __bfloat162float(Q[(size_t)(b * MM + mt * 64 + r) * HH + head * 64 + c]);
    }
    __syncthreads();

    float acc[4][4] = {};
    for (int dp = 0; dp < 64; ++dp) {
        float qv[4], sv[4];
#pragma unroll
        for (int i = 0; i < 4; ++i) qv[i] = Ql[(mb + i) * 64 + dp];
#pragma unroll
        for (int j = 0; j < 4; ++j) sv[j] = Sl[dp * 64 + db + j];
#pragma unroll
        for (int i = 0; i < 4; ++i)
#pragma unroll
            for (int j = 0; j < 4; ++j)
                acc[i][j] += qv[i] * sv[j];
    }

#pragma unroll
    for (int i = 0; i < 4; ++i)
#pragma unroll
        for (int j = 0; j < 4; ++j)
            Out[(size_t)(b * MM + mt * 64 + mb + i) * HH + head * 64 + db + j] =
                __float2bfloat16(acc[i][j]);
}

// ---------------------------------------------------------------------------
extern "C" void kernel_launch(void* const* d_in, const int* in_sizes, int n_in,
                              void* d_out, int out_size, void* d_ws, size_t ws_size,
                              hipStream_t stream) {
    // All inputs are FLOAT32 per the reference dtypes.
    const float* h_f       = (const float*)d_in[0];
    const float* h_cache_f = (const float*)d_in[1];
    // d_in[2] = key_pe: DEAD (softmax result unused by the reference output)
    const float* Wq_f = (const float*)d_in[3];
    const float* Wk_f = (const float*)d_in[4];
    const float* Wv_f = (const float*)d_in[5];
    const float* Wo_f = (const float*)d_in[6];
    float* out = (float*)d_out;  // float32 output

    const int   n_act = BB * MM * HH;       // 4,194,304
    const int   n_w   = HH * HH;            // 1,048,576
    const size_t act_b = (size_t)n_act * 2; // 8 MB bf16
    const size_t w_b   = (size_t)n_w * 2;   // 2 MB bf16

    char* ws = (char*)d_ws;
    __hip_bfloat16* hb   = (__hip_bfloat16*)(ws);
    __hip_bfloat16* hcb  = (__hip_bfloat16*)(ws + act_b);
    __hip_bfloat16* wqb  = (__hip_bfloat16*)(ws + 2 * act_b);
    __hip_bfloat16* wkb  = (__hip_bfloat16*)(ws + 2 * act_b + w_b);
    __hip_bfloat16* wvb  = (__hip_bfloat16*)(ws + 2 * act_b + 2 * w_b);
    __hip_bfloat16* wob  = (__hip_bfloat16*)(ws + 2 * act_b + 3 * w_b);
    __hip_bfloat16* Qbuf = (__hip_bfloat16*)(ws + 2 * act_b + 4 * w_b);
    __hip_bfloat16* Kbuf = (__hip_bfloat16*)(ws + 3 * act_b + 4 * w_b);
    __hip_bfloat16* Vbuf = (__hip_bfloat16*)(ws + 4 * act_b + 4 * w_b);
    float*          Sbuf = (float*)(ws + 5 * act_b + 4 * w_b);  // [B,KH,64,64] f32
    __hip_bfloat16* Outbuf = Kbuf;  // alias: Kbuf dead after kv_outer

    const dim3 blk(256);
    const int Mrows = BB * MM;  // 4096

    // 0: fp32 -> bf16 conversions
    cvt_f32_bf16<<<dim3(n_act / 4 / 256), blk, 0, stream>>>(h_f,       hb,  n_act);
    cvt_f32_bf16<<<dim3(n_act / 4 / 256), blk, 0, stream>>>(h_cache_f, hcb, n_act);
    cvt_f32_bf16<<<dim3(n_w   / 4 / 256), blk, 0, stream>>>(Wq_f, wqb, n_w);
    cvt_f32_bf16<<<dim3(n_w   / 4 / 256), blk, 0, stream>>>(Wk_f, wkb, n_w);
    cvt_f32_bf16<<<dim3(n_w   / 4 / 256), blk, 0, stream>>>(Wv_f, wvb, n_w);
    cvt_f32_bf16<<<dim3(n_w   / 4 / 256), blk, 0, stream>>>(Wo_f, wob, n_w);

    // 1-3: projections (NT GEMMs, weights stored [H,H] row-major = [n,k])
    gemm_nt<<<dim3(Mrows / 128, HH / 128), blk, 0, stream>>>(hb,  wqb, Qbuf, Mrows, HH, HH);
    gemm_nt<<<dim3(Mrows / 128, HH / 128), blk, 0, stream>>>(hcb, wkb, Kbuf, Mrows, HH, HH);
    gemm_nt<<<dim3(Mrows / 128, HH / 128), blk, 0, stream>>>(hcb, wvb, Vbuf, Mrows, HH, HH);

    // 4: S = K^T V per head (zero first; ws is poisoned 0xAA before every call)
    hipMemsetAsync(Sbuf, 0, (size_t)BB * KH * 64 * 64 * sizeof(float), stream);
    kv_outer<<<dim3(8, KH, BB), blk, 0, stream>>>(Kbuf, Vbuf, Sbuf);

    // 5: Out = Q @ blockdiag(S)   (writes into Kbuf region — Kbuf is dead now)
    q_times_s<<<dim3(MM / 64, KH, BB), blk, 0, stream>>>(Qbuf, Sbuf, Outbuf);

    // 6: final = Out @ Wo^T -> d_out (fp32 store)
    gemm_nt<<<dim3(Mrows / 128, HH / 128), blk, 0, stream>>>(Outbuf, wob, out, Mrows, HH, HH);
}

// Round 3
// 202.321 us; speedup vs baseline: 1.3219x; 1.3219x over previous
//
#include <hip/hip_runtime.h>
#include <hip/hip_bf16.h>

// Problem dims (fixed): B=2, M=L=2048, H=1024, K_HEADS=16, D=64
// All inputs/output are FLOAT32; compute in bf16 MFMA with f32 accumulation.
// Algebra: softmax branch is dead; out = Q (K^T V) blockdiag, folded as
//   T = K^T V (per head, 64x64) ; W2[n][h*64+dp] = sum_d Wo[n][h*64+d] T[h][dp][d]
//   final = Q @ W2^T   (one NT GEMM per batch)
#define BB 2
#define MM 2048
#define HH 1024
#define KH 16

typedef short s16x8 __attribute__((ext_vector_type(8)));
typedef float f32x4 __attribute__((ext_vector_type(4)));

#define GLOBAL_AS __attribute__((address_space(1)))
#define LDS_AS    __attribute__((address_space(3)))

__device__ __forceinline__ void async_copy16(const void* g, void* l) {
    __builtin_amdgcn_global_load_lds((const GLOBAL_AS void*)g, (LDS_AS void*)l, 16, 0, 0);
}

struct __align__(8) bf16x4_t { __hip_bfloat16 x, y, z, w; };

// ---------------------------------------------------------------------------
// fused fp32 -> bf16 conversion: grid (4096, 6); seg 0-1 acts, 2-5 weights
// ---------------------------------------------------------------------------
__global__ __launch_bounds__(256) void cvt6(
    const float* __restrict__ s0, const float* __restrict__ s1,
    const float* __restrict__ s2, const float* __restrict__ s3,
    const float* __restrict__ s4, const float* __restrict__ s5,
    __hip_bfloat16* __restrict__ d0, __hip_bfloat16* __restrict__ d1,
    __hip_bfloat16* __restrict__ d2, __hip_bfloat16* __restrict__ d3,
    __hip_bfloat16* __restrict__ d4, __hip_bfloat16* __restrict__ d5)
{
    const int seg = blockIdx.y;
    const float* src;
    __hip_bfloat16* dst;
    int n;
    switch (seg) {
        case 0: src = s0; dst = d0; n = BB * MM * HH; break;
        case 1: src = s1; dst = d1; n = BB * MM * HH; break;
        case 2: src = s2; dst = d2; n = HH * HH; break;
        case 3: src = s3; dst = d3; n = HH * HH; break;
        case 4: src = s4; dst = d4; n = HH * HH; break;
        default: src = s5; dst = d5; n = HH * HH; break;
    }
    const int i = (blockIdx.x * 256 + threadIdx.x) * 4;
    if (i + 3 < n) {
        const float4 v = *(const float4*)(src + i);
        bf16x4_t o;
        o.x = __float2bfloat16(v.x);
        o.y = __float2bfloat16(v.y);
        o.z = __float2bfloat16(v.z);
        o.w = __float2bfloat16(v.w);
        *(bf16x4_t*)(dst + i) = o;
    }
}

// ---------------------------------------------------------------------------
// NT GEMM body: C[m,n] = sum_k A[m,k]*Bm[n,k]; Ncols=Kdim=HH compile-time.
// 128x128 tile, BK=32, global_load_lds w16, 16x16x32 bf16 MFMA (m97 structure)
// ---------------------------------------------------------------------------
__device__ __forceinline__ void store_c(__hip_bfloat16* C, size_t idx, float v) {
    C[idx] = __float2bfloat16(v);
}
__device__ __forceinline__ void store_c(float* C, size_t idx, float v) { C[idx] = v; }

template <typename OutT>
__device__ __forceinline__ void gemm_nt_body(
    const __hip_bfloat16* __restrict__ A,
    const __hip_bfloat16* __restrict__ Bm,
    OutT* __restrict__ C,
    __hip_bfloat16* As, __hip_bfloat16* Bs,
    int m0, int n0)
{
    const int t    = threadIdx.x;
    const int lane = t & 63;
    const int wave = t >> 6;

    const int lr = lane >> 2;          // staging row within 16-row chunk
    const int lc = (lane & 3) * 8;     // staging col (elements)

    const int wm = (wave >> 1) * 64;
    const int wn = (wave & 1) * 64;
    const int fr = lane & 15;
    const int fq = (lane >> 4) * 8;

    f32x4 acc[4][4] = {};

    for (int k0 = 0; k0 < HH; k0 += 32) {
        __syncthreads();
#pragma unroll
        for (int i = 0; i < 2; ++i) {
            const int c = wave * 2 + i;
            async_copy16(A  + (size_t)(m0 + c * 16 + lr) * HH + (k0 + lc), As + c * 512);
            async_copy16(Bm + (size_t)(n0 + c * 16 + lr) * HH + (k0 + lc), Bs + c * 512);
        }
        __syncthreads();

        s16x8 af[4], bf[4];
#pragma unroll
        for (int mi = 0; mi < 4; ++mi)
            af[mi] = *(const s16x8*)(As + (wm + mi * 16 + fr) * 32 + fq);
#pragma unroll
        for (int ni = 0; ni < 4; ++ni)
            bf[ni] = *(const s16x8*)(Bs + (wn + ni * 16 + fr) * 32 + fq);
#pragma unroll
        for (int mi = 0; mi < 4; ++mi)
#pragma unroll
            for (int ni = 0; ni < 4; ++ni)
                acc[mi][ni] = __builtin_amdgcn_mfma_f32_16x16x32_bf16(
                    af[mi], bf[ni], acc[mi][ni], 0, 0, 0);
    }

    const int er = (lane >> 4) * 4;
    const int ec = lane & 15;
#pragma unroll
    for (int mi = 0; mi < 4; ++mi)
#pragma unroll
        for (int ni = 0; ni < 4; ++ni)
#pragma unroll
            for (int r = 0; r < 4; ++r) {
                const int m = m0 + wm + mi * 16 + er + r;
                const int n = n0 + wn + ni * 16 + ec;
                store_c(C, (size_t)m * HH + n, acc[mi][ni][r]);
            }
}

// fused Q/K/V projections: grid (32, 8, 3)
__global__ __launch_bounds__(256) void gemm_qkv(
    const __hip_bfloat16* __restrict__ hb,  const __hip_bfloat16* __restrict__ hcb,
    const __hip_bfloat16* __restrict__ wq,  const __hip_bfloat16* __restrict__ wk,
    const __hip_bfloat16* __restrict__ wv,
    __hip_bfloat16* __restrict__ Q, __hip_bfloat16* __restrict__ K,
    __hip_bfloat16* __restrict__ V)
{
    __shared__ __align__(16) __hip_bfloat16 As[128 * 32];
    __shared__ __align__(16) __hip_bfloat16 Bs[128 * 32];
    const int z = blockIdx.z;
    const __hip_bfloat16* A  = (z == 0) ? hb : hcb;
    const __hip_bfloat16* Bm = (z == 0) ? wq : (z == 1) ? wk : wv;
    __hip_bfloat16* C        = (z == 0) ? Q  : (z == 1) ? K  : V;
    gemm_nt_body(A, Bm, C, As, Bs, blockIdx.x * 128, blockIdx.y * 128);
}

// final GEMM: out[b] = Q[b] @ W2[b]^T, fp32 store; grid (16, 8, 2)
__global__ __launch_bounds__(256) void gemm_final(
    const __hip_bfloat16* __restrict__ Q, const __hip_bfloat16* __restrict__ W2,
    float* __restrict__ out)
{
    __shared__ __align__(16) __hip_bfloat16 As[128 * 32];
    __shared__ __align__(16) __hip_bfloat16 Bs[128 * 32];
    const int b = blockIdx.z;
    gemm_nt_body(Q + (size_t)b * MM * HH, W2 + (size_t)b * HH * HH,
                 out + (size_t)b * MM * HH, As, Bs,
                 blockIdx.x * 128, blockIdx.y * 128);
}

// ---------------------------------------------------------------------------
// T[b,h,d1,d2] = sum_l K[b,l,h*64+d1] * V[b,l,h*64+d2]  (f32 atomic partials)
// grid (16 L-chunks of 128, KH, BB), block 256; LDS stride 68 (bank-clean)
// ---------------------------------------------------------------------------
__global__ __launch_bounds__(256) void kv_outer2(
    const __hip_bfloat16* __restrict__ Km,
    const __hip_bfloat16* __restrict__ Vm,
    float* __restrict__ S)
{
    __shared__ float Kl[128 * 68];  // 34 KB
    __shared__ float Vl[128 * 68];  // 34 KB
    const int t = threadIdx.x, head = blockIdx.y, b = blockIdx.z;
    const int l0 = blockIdx.x * 128;

    // stage 128 l-rows x 64 cols of K and V (bf16x8 loads, f32 LDS)
    for (int idx = t; idx < 1024; idx += 256) {
        const int r = idx >> 3, c8 = (idx & 7) * 8;
        const size_t g = (size_t)(b * MM + l0 + r) * HH + head * 64 + c8;
        s16x8 kv = *(const s16x8*)(Km + g);
        s16x8 vv = *(const s16x8*)(Vm + g);
#pragma unroll
        for (int j = 0; j < 8; ++j) {
            __hip_bfloat16 kb = *(((const __hip_bfloat16*)&kv) + j);
            __hip_bfloat16 vb = *(((const __hip_bfloat16*)&vv) + j);
            Kl[r * 68 + c8 + j] = __bfloat162float(kb);
            Vl[r * 68 + c8 + j] = __bfloat162float(vb);
        }
    }
    __syncthreads();

    const int d1b = (t >> 4) * 4;   // 16 groups x 4 = 64 d1
    const int d2b = (t & 15) * 4;   // 16 groups x 4 = 64 d2
    float acc[4][4] = {};
#pragma unroll 4
    for (int l = 0; l < 128; ++l) {
        const f32x4 kv = *(const f32x4*)(Kl + l * 68 + d1b);
        const f32x4 vv = *(const f32x4*)(Vl + l * 68 + d2b);
#pragma unroll
        for (int i = 0; i < 4; ++i)
#pragma unroll
            for (int j = 0; j < 4; ++j)
                acc[i][j] += kv[i] * vv[j];
    }

    float* Sg = S + ((size_t)b * KH + head) * 4096;
#pragma unroll
    for (int i = 0; i < 4; ++i)
#pragma unroll
        for (int j = 0; j < 4; ++j)
            atomicAdd(&Sg[(d1b + i) * 64 + (d2b + j)], acc[i][j]);
}

// ---------------------------------------------------------------------------
// W2[b][n][h*64+dp] = sum_d Wo[n][h*64+d] * T[b,h,dp,d]   (bf16 out)
// grid (8 n-tiles of 128, KH, BB), block 256
// ---------------------------------------------------------------------------
__global__ __launch_bounds__(256) void w2_fold(
    const __hip_bfloat16* __restrict__ Wo,
    const float* __restrict__ S,
    __hip_bfloat16* __restrict__ W2)
{
    __shared__ float Sl[64 * 68];   // Sl[d*68+dp] = T[dp][d] transposed, 17 KB
    __shared__ float Wl[128 * 68];  // Wl[r*68+d], 34 KB
    const int t = threadIdx.x, head = blockIdx.y, b = blockIdx.z;
    const int n0 = blockIdx.x * 128;

    const float* Sg = S + ((size_t)b * KH + head) * 4096;
    for (int idx = t; idx < 4096; idx += 256) {
        const int dp = idx >> 6, d = idx & 63;
        Sl[d * 68 + dp] = Sg[idx];
    }
    for (int idx = t; idx < 1024; idx += 256) {
        const int r = idx >> 3, c8 = (idx & 7) * 8;
        s16x8 wv = *(const s16x8*)(Wo + (size_t)(n0 + r) * HH + head * 64 + c8);
#pragma unroll
        for (int j = 0; j < 8; ++j) {
            __hip_bfloat16 wb = *(((const __hip_bfloat16*)&wv) + j);
            Wl[r * 68 + c8 + j] = __bfloat162float(wb);
        }
    }
    __syncthreads();

    const int dpb = (t & 15) * 4;   // 4 dp
    const int ng  = t >> 4;         // n rows: ng + 16*i
    float acc[8][4] = {};
    for (int d0 = 0; d0 < 64; d0 += 4) {
        f32x4 sv[4];
#pragma unroll
        for (int r = 0; r < 4; ++r)
            sv[r] = *(const f32x4*)(Sl + (d0 + r) * 68 + dpb);
#pragma unroll
        for (int i = 0; i < 8; ++i) {
            const f32x4 wv = *(const f32x4*)(Wl + (ng + 16 * i) * 68 + d0);
#pragma unroll
            for (int r = 0; r < 4; ++r)
#pragma unroll
                for (int j = 0; j < 4; ++j)
                    acc[i][j] += wv[r] * sv[r][j];
        }
    }

#pragma unroll
    for (int i = 0; i < 8; ++i) {
        bf16x4_t o;
        o.x = __float2bfloat16(acc[i][0]);
        o.y = __float2bfloat16(acc[i][1]);
        o.z = __float2bfloat16(acc[i][2]);
        o.w = __float2bfloat16(acc[i][3]);
        *(bf16x4_t*)(W2 + (size_t)b * HH * HH + (size_t)(n0 + ng + 16 * i) * HH
                     + head * 64 + dpb) = o;
    }
}

// ---------------------------------------------------------------------------
extern "C" void kernel_launch(void* const* d_in, const int* in_sizes, int n_in,
                              void* d_out, int out_size, void* d_ws, size_t ws_size,
                              hipStream_t stream) {
    const float* h_f  = (const float*)d_in[0];
    const float* hc_f = (const float*)d_in[1];
    // d_in[2] = key_pe: DEAD (softmax result unused by reference output)
    const float* Wq_f = (const float*)d_in[3];
    const float* Wk_f = (const float*)d_in[4];
    const float* Wv_f = (const float*)d_in[5];
    const float* Wo_f = (const float*)d_in[6];
    float* out = (float*)d_out;

    const size_t act_b = (size_t)BB * MM * HH * 2;  // 8 MB
    const size_t w_b   = (size_t)HH * HH * 2;       // 2 MB
    char* ws = (char*)d_ws;
    __hip_bfloat16* hb   = (__hip_bfloat16*)(ws);
    __hip_bfloat16* hcb  = (__hip_bfloat16*)(ws + act_b);
    __hip_bfloat16* wqb  = (__hip_bfloat16*)(ws + 2 * act_b);
    __hip_bfloat16* wkb  = (__hip_bfloat16*)(ws + 2 * act_b + w_b);
    __hip_bfloat16* wvb  = (__hip_bfloat16*)(ws + 2 * act_b + 2 * w_b);
    __hip_bfloat16* wob  = (__hip_bfloat16*)(ws + 2 * act_b + 3 * w_b);
    __hip_bfloat16* Qbuf = (__hip_bfloat16*)(ws + 2 * act_b + 4 * w_b);
    __hip_bfloat16* Kbuf = (__hip_bfloat16*)(ws + 3 * act_b + 4 * w_b);
    __hip_bfloat16* Vbuf = (__hip_bfloat16*)(ws + 4 * act_b + 4 * w_b);
    float*          Sbuf = (float*)(ws + 5 * act_b + 4 * w_b);            // 512 KB
    __hip_bfloat16* W2   = (__hip_bfloat16*)(ws + 5 * act_b + 4 * w_b + (size_t)512 * 1024);

    const dim3 blk(256);

    // 0: all fp32->bf16 converts in one dispatch
    cvt6<<<dim3(4096, 6), blk, 0, stream>>>(h_f, hc_f, Wq_f, Wk_f, Wv_f, Wo_f,
                                            hb, hcb, wqb, wkb, wvb, wob);

    // 1: fused Q/K/V projections (768 blocks = 3/CU)
    gemm_qkv<<<dim3(32, 8, 3), blk, 0, stream>>>(hb, hcb, wqb, wkb, wvb,
                                                 Qbuf, Kbuf, Vbuf);

    // 2: T = K^T V per head
    hipMemsetAsync(Sbuf, 0, (size_t)BB * KH * 64 * 64 * sizeof(float), stream);
    kv_outer2<<<dim3(16, KH, BB), blk, 0, stream>>>(Kbuf, Vbuf, Sbuf);

    // 3: W2 = blockdiag(T) folded into Wo
    w2_fold<<<dim3(8, KH, BB), blk, 0, stream>>>(wob, Sbuf, W2);

    // 4: final = Q @ W2^T (fp32 out)
    gemm_final<<<dim3(16, 8, 2), blk, 0, stream>>>(Qbuf, W2, out);
}

// Round 4
// 173.874 us; speedup vs baseline: 1.5381x; 1.1636x over previous
//
#include <hip/hip_runtime.h>
#include <hip/hip_bf16.h>

// Problem dims (fixed): B=2, M=L=2048, H=1024, K_HEADS=16, D=64
// All inputs/output are FLOAT32; compute in bf16 MFMA with f32 accumulation.
// Algebra: softmax branch is dead; out = Q (K^T V) blockdiag, folded as
//   T = K^T V (per head, 64x64) ; W2[n][h*64+dp] = sum_d Wo[n][h*64+d] T[h][dp][d]
//   final = Q @ W2^T   (one NT GEMM per batch)
#define BB 2
#define MM 2048
#define HH 1024
#define KH 16

typedef short s16x8 __attribute__((ext_vector_type(8)));
typedef float f32x4 __attribute__((ext_vector_type(4)));

#define GLOBAL_AS __attribute__((address_space(1)))
#define LDS_AS    __attribute__((address_space(3)))

__device__ __forceinline__ void async_copy16(const void* g, void* l) {
    __builtin_amdgcn_global_load_lds((const GLOBAL_AS void*)g, (LDS_AS void*)l, 16, 0, 0);
}

struct __align__(8) bf16x4_t { __hip_bfloat16 x, y, z, w; };

// ---------------------------------------------------------------------------
// fused fp32 -> bf16 conversion + Sbuf zeroing: grid (4096, 7)
// seg 0-1: activations, 2-5: weights, 6: zero Sbuf (f32)
// ---------------------------------------------------------------------------
__global__ __launch_bounds__(256) void cvt7(
    const float* __restrict__ s0, const float* __restrict__ s1,
    const float* __restrict__ s2, const float* __restrict__ s3,
    const float* __restrict__ s4, const float* __restrict__ s5,
    __hip_bfloat16* __restrict__ d0, __hip_bfloat16* __restrict__ d1,
    __hip_bfloat16* __restrict__ d2, __hip_bfloat16* __restrict__ d3,
    __hip_bfloat16* __restrict__ d4, __hip_bfloat16* __restrict__ d5,
    float* __restrict__ Sz)
{
    const int seg = blockIdx.y;
    const int i = (blockIdx.x * 256 + threadIdx.x) * 4;
    if (seg == 6) {  // zero T accumulator: BB*KH*64*64 = 131072 floats
        if (i + 3 < BB * KH * 64 * 64) {
            float4 z = {0.f, 0.f, 0.f, 0.f};
            *(float4*)(Sz + i) = z;
        }
        return;
    }
    const float* src;
    __hip_bfloat16* dst;
    int n;
    switch (seg) {
        case 0: src = s0; dst = d0; n = BB * MM * HH; break;
        case 1: src = s1; dst = d1; n = BB * MM * HH; break;
        case 2: src = s2; dst = d2; n = HH * HH; break;
        case 3: src = s3; dst = d3; n = HH * HH; break;
        case 4: src = s4; dst = d4; n = HH * HH; break;
        default: src = s5; dst = d5; n = HH * HH; break;
    }
    if (i + 3 < n) {
        const float4 v = *(const float4*)(src + i);
        bf16x4_t o;
        o.x = __float2bfloat16(v.x);
        o.y = __float2bfloat16(v.y);
        o.z = __float2bfloat16(v.z);
        o.w = __float2bfloat16(v.w);
        *(bf16x4_t*)(dst + i) = o;
    }
}

// ---------------------------------------------------------------------------
// NT GEMM 128x128 body (m97 structure): C[m,n] = sum_k A[m,k]*Bm[n,k], Kdim=HH
// ---------------------------------------------------------------------------
__device__ __forceinline__ void store_c(__hip_bfloat16* C, size_t idx, float v) {
    C[idx] = __float2bfloat16(v);
}
__device__ __forceinline__ void store_c(float* C, size_t idx, float v) { C[idx] = v; }

template <typename OutT>
__device__ __forceinline__ void gemm_nt_body(
    const __hip_bfloat16* __restrict__ A,
    const __hip_bfloat16* __restrict__ Bm,
    OutT* __restrict__ C,
    __hip_bfloat16* As, __hip_bfloat16* Bs,
    int m0, int n0)
{
    const int t    = threadIdx.x;
    const int lane = t & 63;
    const int wave = t >> 6;

    const int lr = lane >> 2;
    const int lc = (lane & 3) * 8;

    const int wm = (wave >> 1) * 64;
    const int wn = (wave & 1) * 64;
    const int fr = lane & 15;
    const int fq = (lane >> 4) * 8;

    f32x4 acc[4][4] = {};

    for (int k0 = 0; k0 < HH; k0 += 32) {
        __syncthreads();
#pragma unroll
        for (int i = 0; i < 2; ++i) {
            const int c = wave * 2 + i;
            async_copy16(A  + (size_t)(m0 + c * 16 + lr) * HH + (k0 + lc), As + c * 512);
            async_copy16(Bm + (size_t)(n0 + c * 16 + lr) * HH + (k0 + lc), Bs + c * 512);
        }
        __syncthreads();

        s16x8 af[4], bf[4];
#pragma unroll
        for (int mi = 0; mi < 4; ++mi)
            af[mi] = *(const s16x8*)(As + (wm + mi * 16 + fr) * 32 + fq);
#pragma unroll
        for (int ni = 0; ni < 4; ++ni)
            bf[ni] = *(const s16x8*)(Bs + (wn + ni * 16 + fr) * 32 + fq);
#pragma unroll
        for (int mi = 0; mi < 4; ++mi)
#pragma unroll
            for (int ni = 0; ni < 4; ++ni)
                acc[mi][ni] = __builtin_amdgcn_mfma_f32_16x16x32_bf16(
                    af[mi], bf[ni], acc[mi][ni], 0, 0, 0);
    }

    const int er = (lane >> 4) * 4;
    const int ec = lane & 15;
#pragma unroll
    for (int mi = 0; mi < 4; ++mi)
#pragma unroll
        for (int ni = 0; ni < 4; ++ni)
#pragma unroll
            for (int r = 0; r < 4; ++r) {
                const int m = m0 + wm + mi * 16 + er + r;
                const int n = n0 + wn + ni * 16 + ec;
                store_c(C, (size_t)m * HH + n, acc[mi][ni][r]);
            }
}

// fused Q/K/V projections: grid (32, 8, 3) = 768 blocks (3/CU)
__global__ __launch_bounds__(256) void gemm_qkv(
    const __hip_bfloat16* __restrict__ hb,  const __hip_bfloat16* __restrict__ hcb,
    const __hip_bfloat16* __restrict__ wq,  const __hip_bfloat16* __restrict__ wk,
    const __hip_bfloat16* __restrict__ wv,
    __hip_bfloat16* __restrict__ Q, __hip_bfloat16* __restrict__ K,
    __hip_bfloat16* __restrict__ V)
{
    __shared__ __align__(16) __hip_bfloat16 As[128 * 32];
    __shared__ __align__(16) __hip_bfloat16 Bs[128 * 32];
    const int z = blockIdx.z;
    const __hip_bfloat16* A  = (z == 0) ? hb : hcb;
    const __hip_bfloat16* Bm = (z == 0) ? wq : (z == 1) ? wk : wv;
    __hip_bfloat16* C        = (z == 0) ? Q  : (z == 1) ? K  : V;
    gemm_nt_body(A, Bm, C, As, Bs, blockIdx.x * 128, blockIdx.y * 128);
}

// ---------------------------------------------------------------------------
// final GEMM, 64x128 tile for 2 blocks/CU: out[b] = Q[b] @ W2[b]^T (fp32)
// grid (32, 8, 2) = 512 blocks; wave w: all 64 m-rows x n-cols [w*32, w*32+32)
// ---------------------------------------------------------------------------
__global__ __launch_bounds__(256) void gemm_final(
    const __hip_bfloat16* __restrict__ Qg, const __hip_bfloat16* __restrict__ W2g,
    float* __restrict__ outg)
{
    __shared__ __align__(16) __hip_bfloat16 As[64 * 32];    // 4 KB
    __shared__ __align__(16) __hip_bfloat16 Bs[128 * 32];   // 8 KB

    const int b = blockIdx.z;
    const __hip_bfloat16* A  = Qg  + (size_t)b * MM * HH;
    const __hip_bfloat16* Bm = W2g + (size_t)b * HH * HH;
    float* C                 = outg + (size_t)b * MM * HH;
    const int m0 = blockIdx.x * 64;
    const int n0 = blockIdx.y * 128;

    const int t    = threadIdx.x;
    const int lane = t & 63;
    const int wave = t >> 6;
    const int lr = lane >> 2;
    const int lc = (lane & 3) * 8;
    const int fr = lane & 15;
    const int fq = (lane >> 4) * 8;

    f32x4 acc[4][2] = {};

    for (int k0 = 0; k0 < HH; k0 += 32) {
        __syncthreads();
        // 12 staging chunks: wave stages A-chunk `wave` and B-chunks 2w, 2w+1
        async_copy16(A  + (size_t)(m0 + wave * 16 + lr) * HH + (k0 + lc),
                     As + wave * 512);
        async_copy16(Bm + (size_t)(n0 + (2 * wave) * 16 + lr) * HH + (k0 + lc),
                     Bs + (2 * wave) * 512);
        async_copy16(Bm + (size_t)(n0 + (2 * wave + 1) * 16 + lr) * HH + (k0 + lc),
                     Bs + (2 * wave + 1) * 512);
        __syncthreads();

        s16x8 af[4], bf[2];
#pragma unroll
        for (int mi = 0; mi < 4; ++mi)
            af[mi] = *(const s16x8*)(As + (mi * 16 + fr) * 32 + fq);
#pragma unroll
        for (int ni = 0; ni < 2; ++ni)
            bf[ni] = *(const s16x8*)(Bs + (wave * 32 + ni * 16 + fr) * 32 + fq);
#pragma unroll
        for (int mi = 0; mi < 4; ++mi)
#pragma unroll
            for (int ni = 0; ni < 2; ++ni)
                acc[mi][ni] = __builtin_amdgcn_mfma_f32_16x16x32_bf16(
                    af[mi], bf[ni], acc[mi][ni], 0, 0, 0);
    }

    const int er = (lane >> 4) * 4;
    const int ec = lane & 15;
#pragma unroll
    for (int mi = 0; mi < 4; ++mi)
#pragma unroll
        for (int ni = 0; ni < 2; ++ni)
#pragma unroll
            for (int r = 0; r < 4; ++r) {
                const int m = m0 + mi * 16 + er + r;
                const int n = n0 + wave * 32 + ni * 16 + ec;
                C[(size_t)m * HH + n] = acc[mi][ni][r];
            }
}

// ---------------------------------------------------------------------------
// T[b,h,d1,d2] += sum_l K[b,l,h*64+d1] * V[b,l,h*64+d2]  via MFMA.
// K,V staged TRANSPOSED into LDS (pad stride 136: 16B-aligned rows, banks
// spread 4/row -> only 2-way aliasing). grid (16, KH, BB) = 512 blocks.
// A-frag = Kt rows (d1 major), B-frag = Vt rows (d2 major) -> NT MFMA.
// ---------------------------------------------------------------------------
#define CH 128   // l-rows per block
#define LP 136   // padded LDS leading dim (elements)

__global__ __launch_bounds__(256) void kv_outer_mfma(
    const __hip_bfloat16* __restrict__ Km,
    const __hip_bfloat16* __restrict__ Vm,
    float* __restrict__ S)
{
    __shared__ __align__(16) __hip_bfloat16 Kt[64 * LP];  // [d1][l] 17 KB
    __shared__ __align__(16) __hip_bfloat16 Vt[64 * LP];  // [d2][l] 17 KB

    const int t = threadIdx.x, head = blockIdx.y, b = blockIdx.z;
    const int l0 = blockIdx.x * CH;

    // staging: thread t handles l-row r = t&127, col-groups cb+{0,16,32,48}
    const int r  = t & 127;
    const int cb = (t >> 7) * 8;
    const size_t gbase = (size_t)(b * MM + l0 + r) * HH + head * 64;
#pragma unroll
    for (int u = 0; u < 4; ++u) {
        const int c8 = cb + u * 16;
        const s16x8 kv = *(const s16x8*)(Km + gbase + c8);
        const s16x8 vv = *(const s16x8*)(Vm + gbase + c8);
#pragma unroll
        for (int j = 0; j < 8; ++j) {
            Kt[(c8 + j) * LP + r] = ((const __hip_bfloat16*)&kv)[j];
            Vt[(c8 + j) * LP + r] = ((const __hip_bfloat16*)&vv)[j];
        }
    }
    __syncthreads();

    const int wave = t >> 6, lane = t & 63;
    const int fr = lane & 15;            // m (d1) within 16-tile / n (d2)
    const int fq = (lane >> 4) * 8;      // k (l) sub-offset
    const int wm = wave * 16;            // wave's d1-tile

    f32x4 acc[4] = {};
    for (int kk = 0; kk < CH; kk += 32) {
        const s16x8 af = *(const s16x8*)(Kt + (wm + fr) * LP + kk + fq);
        s16x8 bf[4];
#pragma unroll
        for (int nj = 0; nj < 4; ++nj)
            bf[nj] = *(const s16x8*)(Vt + (nj * 16 + fr) * LP + kk + fq);
#pragma unroll
        for (int nj = 0; nj < 4; ++nj)
            acc[nj] = __builtin_amdgcn_mfma_f32_16x16x32_bf16(af, bf[nj], acc[nj], 0, 0, 0);
    }

    float* Sg = S + ((size_t)b * KH + head) * 4096;
    const int er = (lane >> 4) * 4;
    const int ec = lane & 15;
#pragma unroll
    for (int nj = 0; nj < 4; ++nj)
#pragma unroll
        for (int rr = 0; rr < 4; ++rr)
            atomicAdd(&Sg[(wm + er + rr) * 64 + nj * 16 + ec], acc[nj][rr]);
}

// ---------------------------------------------------------------------------
// W2[b][n][h*64+dp] = sum_d Wo[n][h*64+d] * T[b,h,dp,d]   (bf16 out)
// grid (8, KH, BB), block 256
// ---------------------------------------------------------------------------
__global__ __launch_bounds__(256) void w2_fold(
    const __hip_bfloat16* __restrict__ Wo,
    const float* __restrict__ S,
    __hip_bfloat16* __restrict__ W2)
{
    __shared__ float Sl[64 * 68];   // Sl[d*68+dp] = T[dp][d] transposed
    __shared__ float Wl[128 * 68];  // Wl[r*68+d]
    const int t = threadIdx.x, head = blockIdx.y, b = blockIdx.z;
    const int n0 = blockIdx.x * 128;

    const float* Sg = S + ((size_t)b * KH + head) * 4096;
    for (int idx = t; idx < 4096; idx += 256) {
        const int dp = idx >> 6, d = idx & 63;
        Sl[d * 68 + dp] = Sg[idx];
    }
    for (int idx = t; idx < 1024; idx += 256) {
        const int r = idx >> 3, c8 = (idx & 7) * 8;
        s16x8 wv = *(const s16x8*)(Wo + (size_t)(n0 + r) * HH + head * 64 + c8);
#pragma unroll
        for (int j = 0; j < 8; ++j) {
            __hip_bfloat16 wb = *(((const __hip_bfloat16*)&wv) + j);
            Wl[r * 68 + c8 + j] = __bfloat162float(wb);
        }
    }
    __syncthreads();

    const int dpb = (t & 15) * 4;
    const int ng  = t >> 4;
    float acc[8][4] = {};
    for (int d0 = 0; d0 < 64; d0 += 4) {
        f32x4 sv[4];
#pragma unroll
        for (int r = 0; r < 4; ++r)
            sv[r] = *(const f32x4*)(Sl + (d0 + r) * 68 + dpb);
#pragma unroll
        for (int i = 0; i < 8; ++i) {
            const f32x4 wv = *(const f32x4*)(Wl + (ng + 16 * i) * 68 + d0);
#pragma unroll
            for (int r = 0; r < 4; ++r)
#pragma unroll
                for (int j = 0; j < 4; ++j)
                    acc[i][j] += wv[r] * sv[r][j];
        }
    }

#pragma unroll
    for (int i = 0; i < 8; ++i) {
        bf16x4_t o;
        o.x = __float2bfloat16(acc[i][0]);
        o.y = __float2bfloat16(acc[i][1]);
        o.z = __float2bfloat16(acc[i][2]);
        o.w = __float2bfloat16(acc[i][3]);
        *(bf16x4_t*)(W2 + (size_t)b * HH * HH + (size_t)(n0 + ng + 16 * i) * HH
                     + head * 64 + dpb) = o;
    }
}

// ---------------------------------------------------------------------------
extern "C" void kernel_launch(void* const* d_in, const int* in_sizes, int n_in,
                              void* d_out, int out_size, void* d_ws, size_t ws_size,
                              hipStream_t stream) {
    const float* h_f  = (const float*)d_in[0];
    const float* hc_f = (const float*)d_in[1];
    // d_in[2] = key_pe: DEAD (softmax result unused by reference output)
    const float* Wq_f = (const float*)d_in[3];
    const float* Wk_f = (const float*)d_in[4];
    const float* Wv_f = (const float*)d_in[5];
    const float* Wo_f = (const float*)d_in[6];
    float* out = (float*)d_out;

    const size_t act_b = (size_t)BB * MM * HH * 2;  // 8 MB
    const size_t w_b   = (size_t)HH * HH * 2;       // 2 MB
    char* ws = (char*)d_ws;
    __hip_bfloat16* hb   = (__hip_bfloat16*)(ws);
    __hip_bfloat16* hcb  = (__hip_bfloat16*)(ws + act_b);
    __hip_bfloat16* wqb  = (__hip_bfloat16*)(ws + 2 * act_b);
    __hip_bfloat16* wkb  = (__hip_bfloat16*)(ws + 2 * act_b + w_b);
    __hip_bfloat16* wvb  = (__hip_bfloat16*)(ws + 2 * act_b + 2 * w_b);
    __hip_bfloat16* wob  = (__hip_bfloat16*)(ws + 2 * act_b + 3 * w_b);
    __hip_bfloat16* Qbuf = (__hip_bfloat16*)(ws + 2 * act_b + 4 * w_b);
    __hip_bfloat16* Kbuf = (__hip_bfloat16*)(ws + 3 * act_b + 4 * w_b);
    __hip_bfloat16* Vbuf = (__hip_bfloat16*)(ws + 4 * act_b + 4 * w_b);
    float*          Sbuf = (float*)(ws + 5 * act_b + 4 * w_b);            // 512 KB
    __hip_bfloat16* W2   = (__hip_bfloat16*)(ws + 5 * act_b + 4 * w_b + (size_t)512 * 1024);

    const dim3 blk(256);

    // 0: fp32->bf16 converts + Sbuf zeroing in one dispatch
    cvt7<<<dim3(4096, 7), blk, 0, stream>>>(h_f, hc_f, Wq_f, Wk_f, Wv_f, Wo_f,
                                            hb, hcb, wqb, wkb, wvb, wob, Sbuf);

    // 1: fused Q/K/V projections
    gemm_qkv<<<dim3(32, 8, 3), blk, 0, stream>>>(hb, hcb, wqb, wkb, wvb,
                                                 Qbuf, Kbuf, Vbuf);

    // 2: T = K^T V per head (MFMA, atomic partials into zeroed Sbuf)
    kv_outer_mfma<<<dim3(MM / CH, KH, BB), blk, 0, stream>>>(Kbuf, Vbuf, Sbuf);

    // 3: W2 = blockdiag(T) folded into Wo
    w2_fold<<<dim3(8, KH, BB), blk, 0, stream>>>(wob, Sbuf, W2);

    // 4: final = Q @ W2^T (fp32 out, 512 blocks)
    gemm_final<<<dim3(32, 8, 2), blk, 0, stream>>>(Qbuf, W2, out);
}